// Round 1
// 132.612 us; speedup vs baseline: 1.0578x; 1.0578x over previous
//
#include <hip/hip_runtime.h>
#include <math.h>

// VectorQuantizer via MFMA: in [32,64,64,64] fp32 NCHW (C=D=64), w [512,64] fp32.
// R10: attack the latency-bound K-loop (MfmaUtil 13%, VALUBusy 37%, occ 29%).
//  - B-fragments staged through LDS (double-buffered 8 KB chunks = 32 codes) via
//    global_load_lds_dwordx4, shared by all 4 waves: L2 B-traffic 512->128 MB,
//    per-wave B-reads become ds_read_b128, prefetch window = full chunk.
//  - wn staged to LDS once per block.
//  - s_setprio(1) around each 6-MFMA cluster (independent-phase blocks per CU).
//  - vq_prep widened 8x (32 blocks, 8 threads/code).
// Distance math / tie-break keys / fp64 re-rank / epilogues: verbatim R9 (passed).
typedef short bf16x8 __attribute__((ext_vector_type(8)));
typedef float f32x4 __attribute__((ext_vector_type(4)));

#define VQ_D 64
#define VQ_K 512
#define VQ_NQ 131072
#define VQ_TOTAL 8388608
#define NT 32            // 16-code B tiles (512 / 16)
#define NC 16            // staged chunks (2 tiles = 32 codes = 8 KB each)
#define TAU 8e-3f

typedef __attribute__((address_space(1))) void as1_void;
typedef __attribute__((address_space(3))) void as3_void;

__device__ __forceinline__ void gll16(const void* g, void* l) {
    // global -> LDS direct copy, 16 B per lane; LDS dest = wave-uniform base + lane*16
    __builtin_amdgcn_global_load_lds((as1_void*)(void*)g, (as3_void*)l, 16, 0, 0);
}
__device__ __forceinline__ void gll4(const void* g, void* l) {
    __builtin_amdgcn_global_load_lds((as1_void*)(void*)g, (as3_void*)l, 4, 0, 0);
}

__device__ __forceinline__ ushort bf16_rne(float f) {
    uint u = __builtin_bit_cast(uint, f);
    u += 0x7fffu + ((u >> 16) & 1u);
    return (ushort)(u >> 16);
}
__device__ __forceinline__ float bf16_to_f(ushort h) {
    uint u = ((uint)h) << 16;
    return __builtin_bit_cast(float, u);
}

// ---- prep: w -> bf16 hi/lo in MFMA B-fragment order + fp32 norms + loss=0 ----
// R10: 8 threads per code (one granule each), 32 blocks -- 8x wider than R9's
// 4-block version to shrink the serialized prep tail in front of vq_main.
__global__ __launch_bounds__(128) void vq_prep(const float* __restrict__ w,
                                               ushort* __restrict__ wfrag,
                                               float* __restrict__ wn,
                                               float* __restrict__ out) {
    if (blockIdx.x == 0 && threadIdx.x == 0) out[VQ_TOTAL] = 0.f;
    const int tid = threadIdx.x;
    const int k = (blockIdx.x << 4) + (tid >> 3);   // code index
    const int g = tid & 7;                          // granule: d in [g*8, g*8+8)
    const float4* row = (const float4*)(w + k * VQ_D);
    float4 a = row[2 * g], b4 = row[2 * g + 1];
    float v[8] = {a.x, a.y, a.z, a.w, b4.x, b4.y, b4.z, b4.w};
    ushort hi[8], lo[8];
    float nrm = 0.f;
#pragma unroll
    for (int j = 0; j < 8; ++j) {
        nrm = fmaf(v[j], v[j], nrm);
        hi[j] = bf16_rne(v[j]);
        lo[j] = bf16_rne(v[j] - bf16_to_f(hi[j]));
    }
    // sum ||.||^2 over the code's 8 granules (lanes k*8..k*8+7, same wave)
    nrm += __shfl_xor(nrm, 1, 64);
    nrm += __shfl_xor(nrm, 2, 64);
    nrm += __shfl_xor(nrm, 4, 64);
    if (g == 0) wn[k] = nrm;
    const int t = k >> 4, col = k & 15;
    const int quad = g & 3, fh = g >> 2;
    bf16x8* basez = (bf16x8*)wfrag + t * 256 + quad * 16 + col;
    basez[fh * 64]       = *(bf16x8*)hi;    // bh{fh}
    basez[(2 + fh) * 64] = *(bf16x8*)lo;    // bl{fh}
}

__global__ __launch_bounds__(256, 4) void vq_main(const float* __restrict__ in,
                                                  const float* __restrict__ w,
                                                  const ushort* __restrict__ wfrag,
                                                  const float* __restrict__ wng,
                                                  float* __restrict__ out) {
    __shared__ __align__(16) char bstage[2][8192];   // double-buffered B chunks
    __shared__ float wn_lds[VQ_K];
    __shared__ float xn_lds[128];
    __shared__ float best_lds[128], sec_lds[128];
    __shared__ int   bi_lds[128], si_lds[128];

    const int tid  = threadIdx.x;
    const int lane = tid & 63;
    const int wid  = tid >> 6;
    const int col  = lane & 15;
    const int quad = lane >> 4;
    const int n0  = blockIdx.x * 128;          // block's 128 queries (one image)
    const int b   = n0 >> 12;
    const int hw0 = n0 & 4095;
    const float* xg0 = in + (b << 18) + hw0;
    const float* xgW = xg0 + wid * 32;         // this wave's 32 queries

    // ---- prologue staging: chunk 0 (8 KB) + wn (2 KB); overlaps A-prep ----
    {
        const char* gs = (const char*)wfrag + tid * 16;
        char* lb = &bstage[0][0] + wid * 1024;
        gll16(gs, lb);
        gll16(gs + 4096, lb + 4096);
        gll4(wng + tid,       (char*)wn_lds + wid * 256);
        gll4(wng + 256 + tid, (char*)wn_lds + 1024 + wid * 256);
    }

    // ---- A fragments direct from global (x, bf16 hi/lo) + xnorm (R9 verbatim) ----
    bf16x8 ah0[2], ah1[2], al0[2], al1[2];
#pragma unroll
    for (int T = 0; T < 2; ++T) {
        const float* xq = xgW + T * 16 + col;  // query (wid*32 + T*16 + col)
        float sx = 0.f;
        ushort h0[8], l0[8], h1[8], l1[8];
#pragma unroll
        for (int j = 0; j < 8; ++j) {
            float v0 = xq[(quad * 8 + j) << 12];        // kstep0: d in [0,32)
            float v1 = xq[(32 + quad * 8 + j) << 12];   // kstep1: d in [32,64)
            sx = fmaf(v0, v0, sx);
            sx = fmaf(v1, v1, sx);
            h0[j] = bf16_rne(v0); l0[j] = bf16_rne(v0 - bf16_to_f(h0[j]));
            h1[j] = bf16_rne(v1); l1[j] = bf16_rne(v1 - bf16_to_f(h1[j]));
        }
        ah0[T] = *(bf16x8*)h0; al0[T] = *(bf16x8*)l0;
        ah1[T] = *(bf16x8*)h1; al1[T] = *(bf16x8*)l1;
        sx += __shfl_xor(sx, 16, 64);                   // sum the 4 quads
        sx += __shfl_xor(sx, 32, 64);
        if (quad == 0) xn_lds[wid * 32 + T * 16 + col] = sx;
    }

    __syncthreads();   // drains prologue gll (vmcnt) + xn_lds writes

    // ---- K-loop: B from LDS double buffer; dist = fmaf(-2, dot, wn) (R9 math) ----
    float best[8], sec[8];
#pragma unroll
    for (int r = 0; r < 8; ++r) { best[r] = 3.0e38f; sec[r] = 3.0e38f; }

#pragma unroll 1
    for (int t = 0; t < NC; ++t) {
        char* const bcur = &bstage[t & 1][0];
        if (t + 1 < NC) {                       // prefetch next 8 KB chunk
            const char* gs = (const char*)wfrag + (t + 1) * 8192 + tid * 16;
            char* lb = &bstage[(t + 1) & 1][0] + wid * 1024;
            gll16(gs, lb);
            gll16(gs + 4096, lb + 4096);
        }
#pragma unroll
        for (int s = 0; s < 2; ++s) {           // two 16-code tiles per chunk
            const int t2 = 2 * t + s;
            const char* rb = bcur + s * 4096 + lane * 16;
            bf16x8 bh0 = *(const bf16x8*)(rb);
            bf16x8 bh1 = *(const bf16x8*)(rb + 1024);
            bf16x8 bl0 = *(const bf16x8*)(rb + 2048);
            bf16x8 bl1 = *(const bf16x8*)(rb + 3072);
            const float wnv = wn_lds[t2 * 16 + col];
#pragma unroll
            for (int T = 0; T < 2; ++T) {
                f32x4 accP = {0.f, 0.f, 0.f, 0.f}, accQ = {0.f, 0.f, 0.f, 0.f};
                __builtin_amdgcn_s_setprio(1);
                accP = __builtin_amdgcn_mfma_f32_16x16x32_bf16(ah0[T], bh0, accP, 0, 0, 0);
                accP = __builtin_amdgcn_mfma_f32_16x16x32_bf16(ah1[T], bh1, accP, 0, 0, 0);
                accQ = __builtin_amdgcn_mfma_f32_16x16x32_bf16(ah0[T], bl0, accQ, 0, 0, 0);
                accQ = __builtin_amdgcn_mfma_f32_16x16x32_bf16(ah1[T], bl1, accQ, 0, 0, 0);
                accQ = __builtin_amdgcn_mfma_f32_16x16x32_bf16(al0[T], bh0, accQ, 0, 0, 0);
                accQ = __builtin_amdgcn_mfma_f32_16x16x32_bf16(al1[T], bh1, accQ, 0, 0, 0);
                __builtin_amdgcn_s_setprio(0);
#pragma unroll
                for (int j = 0; j < 4; ++j) {   // C: row(query)=quad*4+j, col=code
                    float dist = fmaf(-2.f, accP[j] + accQ[j], wnv);
                    uint u = (__builtin_bit_cast(uint, dist) & 0xFFFFFFE0u) | (uint)t2;
                    float key = __builtin_bit_cast(float, u);
                    const int r = T * 4 + j;
                    float m = fmaxf(best[r], key);
                    best[r] = fminf(best[r], key);
                    sec[r]  = fminf(sec[r], m);
                }
            }
        }
        __syncthreads();   // chunk t reads done; chunk t+1 staged
    }

    // ---- unpack packed keys -> (dist_class, global code idx) (R9 verbatim) ----
    float bD[8], sD[8];
    int bI[8], sI[8];
#pragma unroll
    for (int r = 0; r < 8; ++r) {
        uint ub = __builtin_bit_cast(uint, best[r]);
        uint us = __builtin_bit_cast(uint, sec[r]);
        bI[r] = (int)(ub & 31u) * 16 + col;
        sI[r] = (int)(us & 31u) * 16 + col;
        bD[r] = __builtin_bit_cast(float, ub & 0xFFFFFFE0u);
        sD[r] = __builtin_bit_cast(float, us & 0xFFFFFFE0u);
    }

    // ---- merge across 16 col-lanes (R9 verbatim) ----
#pragma unroll
    for (int off = 1; off < 16; off <<= 1) {
#pragma unroll
        for (int r = 0; r < 8; ++r) {
            float ob = __shfl_xor(bD[r], off, 64);
            float os = __shfl_xor(sD[r], off, 64);
            int   oi = __shfl_xor(bI[r], off, 64);
            int   oc = __shfl_xor(sI[r], off, 64);
            bool oWins = (ob < bD[r]) || (ob == bD[r] && oi < bI[r]);
            float nb  = oWins ? ob    : bD[r];
            int   ni  = oWins ? oi    : bI[r];
            float c1  = oWins ? bD[r] : ob;      // loser's best
            int   ci1 = oWins ? bI[r] : oi;
            float c2  = oWins ? os    : sD[r];   // winner's second
            int   ci2 = oWins ? oc    : sI[r];
            bool c1w = (c1 < c2) || (c1 == c2 && ci1 < ci2);
            sD[r] = c1w ? c1  : c2;
            sI[r] = c1w ? ci1 : ci2;
            bD[r] = nb; bI[r] = ni;
        }
    }
    if (col == 0) {
#pragma unroll
        for (int r = 0; r < 8; ++r) {           // q in block = wid*32 + T*16 + quad*4 + j
            const int q = wid * 32 + (r >> 2) * 16 + quad * 4 + (r & 3);
            best_lds[q] = bD[r]; sec_lds[q] = sD[r];
            bi_lds[q] = bI[r];   si_lds[q] = sI[r];
        }
    }
    __syncthreads();

    // ---- epilogue (R9 verbatim): per-thread fp64 near-tie re-rank + loss ----
    if (tid < 128) {
        const int q = tid;
        float cb = best_lds[q], cs = sec_lds[q];
        int cbi = bi_lds[q], csi = si_lds[q];
        double chosen = (double)cb;
        if (cs - cb < TAU) {
            const float* wb  = w + cbi * VQ_D;
            const float* ws2 = w + csi * VQ_D;
            const float* xqp = xg0 + q;
            double nb = 0.0, dotb = 0.0, ns = 0.0, dots = 0.0;
            for (int d = 0; d < VQ_D; ++d) {
                double xv = (double)xqp[d << 12];
                double wbv = (double)wb[d], wsv = (double)ws2[d];
                nb = fma(wbv, wbv, nb); dotb = fma(xv, wbv, dotb);
                ns = fma(wsv, wsv, ns); dots = fma(xv, wsv, dots);
            }
            double db = nb - 2.0 * dotb, ds = ns - 2.0 * dots;
            if (ds < db || (ds == db && csi < cbi)) { cbi = csi; chosen = ds; }
            else                                    { chosen = db; }
        }
        bi_lds[q] = cbi;
        double lq = (double)xn_lds[q] + chosen;   // ||x-e||^2 = xnorm + (wn - 2 dot)
#pragma unroll
        for (int off = 32; off > 0; off >>= 1)
            lq += __shfl_down(lq, off, 64);
        if ((tid & 63) == 0)
            atomicAdd(out + VQ_TOTAL, (float)(lq * (1.0 / (double)VQ_TOTAL)));
    }
    __syncthreads();

    // ---- cooperative quantized write (R9 verbatim): 2 threads/query ----
    {
        const int q = tid & 127, half = tid >> 7;  // half covers d in [32*half, +32)
        const float4* wrow = (const float4*)(w + bi_lds[q] * VQ_D) + half * 8;
        float* op = out + (b << 18) + hw0 + q;
#pragma unroll
        for (int u = 0; u < 8; ++u) {
            float4 v = wrow[u];
            const int d = half * 32 + 4 * u;
            op[(d + 0) << 12] = v.x;
            op[(d + 1) << 12] = v.y;
            op[(d + 2) << 12] = v.z;
            op[(d + 3) << 12] = v.w;
        }
    }
}

extern "C" void kernel_launch(void* const* d_in, const int* in_sizes, int n_in,
                              void* d_out, int out_size, void* d_ws, size_t ws_size,
                              hipStream_t stream) {
    const float* in = (const float*)d_in[0];
    const float* w  = (const float*)d_in[1];
    float* out = (float*)d_out;

    ushort* wfrag = (ushort*)d_ws;                    // 512*128 ushort = 128 KB
    float*  wn    = (float*)((char*)d_ws + 131072);   // 512 floats

    vq_prep<<<32, 128, 0, stream>>>(w, wfrag, wn, out);   // also zeroes loss cell
    vq_main<<<VQ_NQ / 128, 256, 0, stream>>>(in, w, wfrag, wn, out);
}

// Round 2
// 116.719 us; speedup vs baseline: 1.2019x; 1.1362x over previous
//
#include <hip/hip_runtime.h>
#include <math.h>

// VectorQuantizer via MFMA: in [32,64,64,64] fp32 NCHW (C=D=64), w [512,64] fp32.
// R11: occupancy attack. R10 was still latency-bound (MfmaUtil 15, VALUBusy 34,
// occ 30) with a structural 4-waves/SIMD cap (32 queries/wave).
//  - 16 queries/wave: 512-thread blocks, 8 waves, same 128 queries/block.
//    8192 waves total = 100% occupancy ceiling (4 blocks/CU, 32 waves/CU).
//  - chunks of 4 tiles (16 KB): 8 barriers/block instead of 16.
//  - fp64 near-tie re-rank split across 4 lanes/query (serial tail / 4).
//  - loss: LDS-combined, 1 atomicAdd per block.
//  - quantized write: 4 threads/query.
// Distance math / key packing / tie-break semantics verbatim from R10 (passed).
typedef short bf16x8 __attribute__((ext_vector_type(8)));
typedef float f32x4 __attribute__((ext_vector_type(4)));

#define VQ_D 64
#define VQ_K 512
#define VQ_NQ 131072
#define VQ_TOTAL 8388608
#define NT 32            // 16-code B tiles (512 / 16)
#define NCK 8            // staged chunks (4 tiles = 64 codes = 16 KB each)
#define TAU 8e-3f

typedef __attribute__((address_space(1))) void as1_void;
typedef __attribute__((address_space(3))) void as3_void;

__device__ __forceinline__ void gll16(const void* g, void* l) {
    // global -> LDS direct copy, 16 B per lane; LDS dest = wave-uniform base + lane*16
    __builtin_amdgcn_global_load_lds((as1_void*)(void*)g, (as3_void*)l, 16, 0, 0);
}
__device__ __forceinline__ void gll4(const void* g, void* l) {
    __builtin_amdgcn_global_load_lds((as1_void*)(void*)g, (as3_void*)l, 4, 0, 0);
}

__device__ __forceinline__ ushort bf16_rne(float f) {
    uint u = __builtin_bit_cast(uint, f);
    u += 0x7fffu + ((u >> 16) & 1u);
    return (ushort)(u >> 16);
}
__device__ __forceinline__ float bf16_to_f(ushort h) {
    uint u = ((uint)h) << 16;
    return __builtin_bit_cast(float, u);
}

// ---- prep: w -> bf16 hi/lo in MFMA B-fragment order + fp32 norms + loss=0 ----
// (verbatim R10: 8 threads per code, 32 blocks)
__global__ __launch_bounds__(128) void vq_prep(const float* __restrict__ w,
                                               ushort* __restrict__ wfrag,
                                               float* __restrict__ wn,
                                               float* __restrict__ out) {
    if (blockIdx.x == 0 && threadIdx.x == 0) out[VQ_TOTAL] = 0.f;
    const int tid = threadIdx.x;
    const int k = (blockIdx.x << 4) + (tid >> 3);   // code index
    const int g = tid & 7;                          // granule: d in [g*8, g*8+8)
    const float4* row = (const float4*)(w + k * VQ_D);
    float4 a = row[2 * g], b4 = row[2 * g + 1];
    float v[8] = {a.x, a.y, a.z, a.w, b4.x, b4.y, b4.z, b4.w};
    ushort hi[8], lo[8];
    float nrm = 0.f;
#pragma unroll
    for (int j = 0; j < 8; ++j) {
        nrm = fmaf(v[j], v[j], nrm);
        hi[j] = bf16_rne(v[j]);
        lo[j] = bf16_rne(v[j] - bf16_to_f(hi[j]));
    }
    // sum ||.||^2 over the code's 8 granules (lanes k*8..k*8+7, same wave)
    nrm += __shfl_xor(nrm, 1, 64);
    nrm += __shfl_xor(nrm, 2, 64);
    nrm += __shfl_xor(nrm, 4, 64);
    if (g == 0) wn[k] = nrm;
    const int t = k >> 4, col = k & 15;
    const int quad = g & 3, fh = g >> 2;
    bf16x8* basez = (bf16x8*)wfrag + t * 256 + quad * 16 + col;
    basez[fh * 64]       = *(bf16x8*)hi;    // bh{fh}
    basez[(2 + fh) * 64] = *(bf16x8*)lo;    // bl{fh}
}

__global__ __launch_bounds__(512, 8) void vq_main(const float* __restrict__ in,
                                                  const float* __restrict__ w,
                                                  const ushort* __restrict__ wfrag,
                                                  const float* __restrict__ wng,
                                                  float* __restrict__ out) {
    __shared__ __align__(16) char bstage[2][16384];  // double-buffered B chunks
    __shared__ float wn_lds[VQ_K];
    __shared__ float xn_lds[128];
    __shared__ float best_lds[128], sec_lds[128];
    __shared__ int   bi_lds[128], si_lds[128];
    __shared__ double loss_lds[8];

    const int tid  = threadIdx.x;
    const int lane = tid & 63;
    const int wid  = tid >> 6;                 // 8 waves
    const int col  = lane & 15;
    const int quad = lane >> 4;
    const int n0  = blockIdx.x * 128;          // block's 128 queries (one image)
    const int b   = n0 >> 12;
    const int hw0 = n0 & 4095;
    const float* xg0 = in + (b << 18) + hw0;

    // ---- prologue staging: chunk 0 (16 KB) + wn (2 KB); overlaps A-prep ----
    {
        const char* gs = (const char*)wfrag + tid * 16;     // per-lane global src
        char* lb = &bstage[0][0] + wid * 1024;              // wave-uniform LDS base
        gll16(gs, lb);
        gll16(gs + 8192, lb + 8192);
        gll4(wng + tid, (char*)wn_lds + wid * 256);         // 512 floats
    }

    // ---- A fragments direct from global (x, bf16 hi/lo) + xnorm ----
    // 16 queries per wave: query = wid*16 + col; A[m=col][k=quad*8+j].
    bf16x8 ah0, ah1, al0, al1;
    {
        const float* xq = xg0 + wid * 16 + col;
        float sx = 0.f;
        ushort h0[8], l0[8], h1[8], l1[8];
#pragma unroll
        for (int j = 0; j < 8; ++j) {
            float v0 = xq[(quad * 8 + j) << 12];        // kstep0: d in [0,32)
            float v1 = xq[(32 + quad * 8 + j) << 12];   // kstep1: d in [32,64)
            sx = fmaf(v0, v0, sx);
            sx = fmaf(v1, v1, sx);
            h0[j] = bf16_rne(v0); l0[j] = bf16_rne(v0 - bf16_to_f(h0[j]));
            h1[j] = bf16_rne(v1); l1[j] = bf16_rne(v1 - bf16_to_f(h1[j]));
        }
        ah0 = *(bf16x8*)h0; al0 = *(bf16x8*)l0;
        ah1 = *(bf16x8*)h1; al1 = *(bf16x8*)l1;
        sx += __shfl_xor(sx, 16, 64);                   // sum the 4 quads
        sx += __shfl_xor(sx, 32, 64);
        if (quad == 0) xn_lds[wid * 16 + col] = sx;
    }

    __syncthreads();   // drains prologue gll (vmcnt) + xn_lds writes

    // ---- K-loop: B from LDS double buffer; dist = fmaf(-2, dot, wn) ----
    float best[4], sec[4];
#pragma unroll
    for (int r = 0; r < 4; ++r) { best[r] = 3.0e38f; sec[r] = 3.0e38f; }

#pragma unroll 1
    for (int c = 0; c < NCK; ++c) {
        char* const bcur = &bstage[c & 1][0];
        if (c + 1 < NCK) {                      // prefetch next 16 KB chunk
            const char* gs = (const char*)wfrag + (c + 1) * 16384 + tid * 16;
            char* lb = &bstage[(c + 1) & 1][0] + wid * 1024;
            gll16(gs, lb);
            gll16(gs + 8192, lb + 8192);
        }
#pragma unroll
        for (int s = 0; s < 4; ++s) {           // four 16-code tiles per chunk
            const int t2 = 4 * c + s;
            const char* rb = bcur + s * 4096 + lane * 16;
            bf16x8 bh0 = *(const bf16x8*)(rb);
            bf16x8 bh1 = *(const bf16x8*)(rb + 1024);
            bf16x8 bl0 = *(const bf16x8*)(rb + 2048);
            bf16x8 bl1 = *(const bf16x8*)(rb + 3072);
            const float wnv = wn_lds[t2 * 16 + col];
            f32x4 accP = {0.f, 0.f, 0.f, 0.f}, accQ = {0.f, 0.f, 0.f, 0.f};
            __builtin_amdgcn_s_setprio(1);
            accP = __builtin_amdgcn_mfma_f32_16x16x32_bf16(ah0, bh0, accP, 0, 0, 0);
            accP = __builtin_amdgcn_mfma_f32_16x16x32_bf16(ah1, bh1, accP, 0, 0, 0);
            accQ = __builtin_amdgcn_mfma_f32_16x16x32_bf16(ah0, bl0, accQ, 0, 0, 0);
            accQ = __builtin_amdgcn_mfma_f32_16x16x32_bf16(ah1, bl1, accQ, 0, 0, 0);
            accQ = __builtin_amdgcn_mfma_f32_16x16x32_bf16(al0, bh0, accQ, 0, 0, 0);
            accQ = __builtin_amdgcn_mfma_f32_16x16x32_bf16(al1, bh1, accQ, 0, 0, 0);
            __builtin_amdgcn_s_setprio(0);
#pragma unroll
            for (int j = 0; j < 4; ++j) {       // C: row(query)=quad*4+j, col=code
                float dist = fmaf(-2.f, accP[j] + accQ[j], wnv);
                uint u = (__builtin_bit_cast(uint, dist) & 0xFFFFFFE0u) | (uint)t2;
                float key = __builtin_bit_cast(float, u);
                float m = fmaxf(best[j], key);
                best[j] = fminf(best[j], key);
                sec[j]  = fminf(sec[j], m);
            }
        }
        __syncthreads();   // chunk c reads done; chunk c+1 staged
    }

    // ---- unpack packed keys -> (dist_class, global code idx) ----
    float bD[4], sD[4];
    int bI[4], sI[4];
#pragma unroll
    for (int r = 0; r < 4; ++r) {
        uint ub = __builtin_bit_cast(uint, best[r]);
        uint us = __builtin_bit_cast(uint, sec[r]);
        bI[r] = (int)(ub & 31u) * 16 + col;
        sI[r] = (int)(us & 31u) * 16 + col;
        bD[r] = __builtin_bit_cast(float, ub & 0xFFFFFFE0u);
        sD[r] = __builtin_bit_cast(float, us & 0xFFFFFFE0u);
    }

    // ---- merge across 16 col-lanes (verbatim semantics) ----
#pragma unroll
    for (int off = 1; off < 16; off <<= 1) {
#pragma unroll
        for (int r = 0; r < 4; ++r) {
            float ob = __shfl_xor(bD[r], off, 64);
            float os = __shfl_xor(sD[r], off, 64);
            int   oi = __shfl_xor(bI[r], off, 64);
            int   oc = __shfl_xor(sI[r], off, 64);
            bool oWins = (ob < bD[r]) || (ob == bD[r] && oi < bI[r]);
            float nb  = oWins ? ob    : bD[r];
            int   ni  = oWins ? oi    : bI[r];
            float c1  = oWins ? bD[r] : ob;      // loser's best
            int   ci1 = oWins ? bI[r] : oi;
            float c2  = oWins ? os    : sD[r];   // winner's second
            int   ci2 = oWins ? oc    : sI[r];
            bool c1w = (c1 < c2) || (c1 == c2 && ci1 < ci2);
            sD[r] = c1w ? c1  : c2;
            sI[r] = c1w ? ci1 : ci2;
            bD[r] = nb; bI[r] = ni;
        }
    }
    if (col == 0) {
#pragma unroll
        for (int r = 0; r < 4; ++r) {           // q in block = wid*16 + quad*4 + r
            const int q = wid * 16 + quad * 4 + r;
            best_lds[q] = bD[r]; sec_lds[q] = sD[r];
            bi_lds[q] = bI[r];   si_lds[q] = sI[r];
        }
    }
    __syncthreads();

    // ---- epilogue: fp64 near-tie re-rank, 4 lanes per query + loss ----
    {
        const int q = tid >> 2, part = tid & 3;   // lanes 4k..4k+3 share query q
        float cb = best_lds[q], cs = sec_lds[q];
        int cbi = bi_lds[q], csi = si_lds[q];
        double chosen = (double)cb;
        if (cs - cb < TAU) {
            const float* wb  = w + cbi * VQ_D + part * 16;
            const float* ws2 = w + csi * VQ_D + part * 16;
            const float* xqp = xg0 + q;
            double nb = 0.0, dotb = 0.0, ns = 0.0, dots = 0.0;
#pragma unroll
            for (int d0 = 0; d0 < 16; ++d0) {
                const int d = part * 16 + d0;
                double xv = (double)xqp[d << 12];
                double wbv = (double)wb[d0], wsv = (double)ws2[d0];
                nb = fma(wbv, wbv, nb); dotb = fma(xv, wbv, dotb);
                ns = fma(wsv, wsv, ns); dots = fma(xv, wsv, dots);
            }
            // combine the 4 partials (butterfly within the 4-lane group)
#pragma unroll
            for (int off = 1; off < 4; off <<= 1) {
                nb   += __shfl_xor(nb,   off, 64);
                dotb += __shfl_xor(dotb, off, 64);
                ns   += __shfl_xor(ns,   off, 64);
                dots += __shfl_xor(dots, off, 64);
            }
            double db = nb - 2.0 * dotb, ds = ns - 2.0 * dots;
            if (ds < db || (ds == db && csi < cbi)) { cbi = csi; chosen = ds; }
            else                                    { chosen = db; }
        }
        if (part == 0) bi_lds[q] = cbi;
        double lq = (part == 0) ? ((double)xn_lds[q] + chosen) : 0.0;
#pragma unroll
        for (int off = 32; off > 0; off >>= 1)
            lq += __shfl_down(lq, off, 64);
        if (lane == 0) loss_lds[wid] = lq;
    }
    __syncthreads();
    if (tid == 0) {
        double s = 0.0;
#pragma unroll
        for (int wv = 0; wv < 8; ++wv) s += loss_lds[wv];
        atomicAdd(out + VQ_TOTAL, (float)(s * (1.0 / (double)VQ_TOTAL)));
    }

    // ---- cooperative quantized write: 4 threads/query ----
    {
        const int q = tid & 127, quarter = tid >> 7;  // quarter: d in [16*quarter, +16)
        const float4* wrow = (const float4*)(w + bi_lds[q] * VQ_D) + quarter * 4;
        float* op = out + (b << 18) + hw0 + q;
#pragma unroll
        for (int u = 0; u < 4; ++u) {
            float4 v = wrow[u];
            const int d = quarter * 16 + 4 * u;
            op[(d + 0) << 12] = v.x;
            op[(d + 1) << 12] = v.y;
            op[(d + 2) << 12] = v.z;
            op[(d + 3) << 12] = v.w;
        }
    }
}

extern "C" void kernel_launch(void* const* d_in, const int* in_sizes, int n_in,
                              void* d_out, int out_size, void* d_ws, size_t ws_size,
                              hipStream_t stream) {
    const float* in = (const float*)d_in[0];
    const float* w  = (const float*)d_in[1];
    float* out = (float*)d_out;

    ushort* wfrag = (ushort*)d_ws;                    // 512*128 ushort = 128 KB
    float*  wn    = (float*)((char*)d_ws + 131072);   // 512 floats

    vq_prep<<<32, 128, 0, stream>>>(w, wfrag, wn, out);   // also zeroes loss cell
    vq_main<<<VQ_NQ / 128, 512, 0, stream>>>(in, w, wfrag, wn, out);
}